// Round 3
// baseline (112881.763 us; speedup 1.0000x reference)
//
#include <hip/hip_runtime.h>
#include <math.h>

#define B_   128
#define T_   256
#define IN_  512
#define C_   2048
#define N_   256
#define M_   128
#define OUT_ 512
#define PR   134          // M_+6
#define PWW  390          // 3M+6
#define PTOT 1036         // PR + PWW + OUT_
#define COLP 1152         // padded P columns (9 tiles of 128)
#define ZP   16           // split-K partials for GEMM2
#define NBLK 256
#define P2BLK 144         // blocks running the P-GEMM in phase 2
#define EPSF 1e-8f

__device__ __forceinline__ float softplusf(float x) { return (x > 20.f) ? x : log1pf(expf(x)); }
__device__ __forceinline__ float sigmoidf(float x) { return 1.f / (1.f + expf(-x)); }

// ---------------- grid-wide barrier (regular launch, all blocks co-resident) ----------------
__device__ __forceinline__ void grid_barrier(unsigned* cnt, unsigned* gen)
{
    __syncthreads();
    if (threadIdx.x == 0) {
        __threadfence();   // release: prior stores visible device-scope
        unsigned g = __hip_atomic_load(gen, __ATOMIC_RELAXED, __HIP_MEMORY_SCOPE_AGENT);
        unsigned a = __hip_atomic_fetch_add(cnt, 1u, __ATOMIC_ACQ_REL, __HIP_MEMORY_SCOPE_AGENT);
        if (a == (unsigned)(NBLK - 1)) {
            __hip_atomic_store(cnt, 0u, __ATOMIC_RELAXED, __HIP_MEMORY_SCOPE_AGENT);
            __hip_atomic_store(gen, g + 1u, __ATOMIC_RELEASE, __HIP_MEMORY_SCOPE_AGENT);
        } else {
            while (__hip_atomic_load(gen, __ATOMIC_ACQUIRE, __HIP_MEMORY_SCOPE_AGENT) == g)
                __builtin_amdgcn_s_sleep(1);
        }
        __threadfence();   // acquire: invalidate stale cached lines
    }
    __syncthreads();
}

// ---------------- init: state + barrier words ----------------
__global__ __launch_bounds__(256) void init_state(
    float* __restrict__ mem, float* __restrict__ w_r, float* __restrict__ w_w,
    float* __restrict__ r, unsigned* __restrict__ bar,
    const float* __restrict__ mem_init, const float* __restrict__ read_init)
{
    int i0 = blockIdx.x * blockDim.x + threadIdx.x;
    int stride = gridDim.x * blockDim.x;
    for (int i = i0; i < B_ * N_ * M_; i += stride)
        mem[i] = mem_init[i & (N_ * M_ - 1)];
    for (int i = i0; i < B_ * N_; i += stride) { w_r[i] = 1.f / N_; w_w[i] = 1.f / N_; }
    for (int i = i0; i < B_ * M_; i += stride) r[i] = read_init[i & (M_ - 1)];
    if (i0 < 2) bar[i0] = 0u;
}

// ---------------- shared-memory union across phases ----------------
struct SM3 { float p[400]; float wsh[N_]; float red[8]; };
union SMem {
    struct { float As[16][36];  float Bs[16][36];  } p1;   // h-GEMM
    struct { float As[16][132]; float Bs[16][132]; } p2;   // P-GEMM / Xc-GEMM
    SM3 p3;                                                // addressing
};

__device__ __forceinline__ float redSum(SM3& s, float v, int slot) {
#pragma unroll
    for (int off = 32; off; off >>= 1) v += __shfl_xor(v, off, 64);
    if ((threadIdx.x & 63) == 0) s.red[slot * 4 + (threadIdx.x >> 6)] = v;
    __syncthreads();
    return (s.red[slot * 4] + s.red[slot * 4 + 1]) + (s.red[slot * 4 + 2] + s.red[slot * 4 + 3]);
}
__device__ __forceinline__ float redMax(SM3& s, float v, int slot) {
#pragma unroll
    for (int off = 32; off; off >>= 1) v = fmaxf(v, __shfl_xor(v, off, 64));
    if ((threadIdx.x & 63) == 0) s.red[slot * 4 + (threadIdx.x >> 6)] = v;
    __syncthreads();
    return fmaxf(fmaxf(s.red[slot * 4], s.red[slot * 4 + 1]),
                 fmaxf(s.red[slot * 4 + 2], s.red[slot * 4 + 3]));
}

// addressing math over s.p[0..134); leaves final w in s.wsh and wglob
__device__ __forceinline__ void compute_w(
    SM3& s, const float* __restrict__ mem, float* __restrict__ wglob, int b)
{
    int tid = threadIdx.x;
    float kv = (tid < M_) ? s.p[tid] : 0.f;
    float knorm = sqrtf(redSum(s, kv * kv, 0));
    float beta = softplusf(s.p[M_]);
    float g    = sigmoidf(s.p[M_ + 1]);
    float a0 = s.p[M_ + 2], a1 = s.p[M_ + 3], a2 = s.p[M_ + 4];
    float mx3 = fmaxf(a0, fmaxf(a1, a2));
    float e0 = expf(a0 - mx3), e1 = expf(a1 - mx3), e2 = expf(a2 - mx3);
    float inv3 = 1.f / (e0 + e1 + e2);
    float s0 = e0 * inv3, s1 = e1 * inv3, s2 = e2 * inv3;
    float gamma = 1.f + softplusf(s.p[M_ + 5]);

    const float* mrow = mem + ((size_t)b * N_ + tid) * M_;
    float dot = 0.f, nrm = 0.f;
#pragma unroll 8
    for (int m = 0; m < M_; m += 4) {
        float4 v = *(const float4*)&mrow[m];
        float4 kk = *(const float4*)&s.p[m];
        dot += v.x * kk.x + v.y * kk.y + v.z * kk.z + v.w * kk.w;
        nrm += v.x * v.x + v.y * v.y + v.z * v.z + v.w * v.w;
    }
    float sim = dot / (knorm * sqrtf(nrm) + EPSF);
    float zz = beta * sim;
    float mx = redMax(s, zz, 1);
    float ez = expf(zz - mx);
    float wc = ez / redSum(s, ez, 0);
    float wgv = g * wc + (1.f - g) * wglob[(size_t)b * N_ + tid];
    s.wsh[tid] = wgv;
    __syncthreads();
    float wt = s0 * s.wsh[(tid + 1) & (N_ - 1)]
             + s1 * wgv
             + s2 * s.wsh[(tid + N_ - 1) & (N_ - 1)];
    float wp = powf(wt + EPSF, gamma);
    float wfin = wp / redSum(s, wp, 1);   // internal barrier covers wsh reads above
    wglob[(size_t)b * N_ + tid] = wfin;
    s.wsh[tid] = wfin;
    __syncthreads();
}

// ---------------- persistent kernel (regular launch): whole T loop ----------------
__global__ __launch_bounds__(256, 1) void ntm_persistent(
    const float* __restrict__ x,  const float* __restrict__ Wc,  const float* __restrict__ bc,
    const float* __restrict__ Wr, const float* __restrict__ br,
    const float* __restrict__ Ww, const float* __restrict__ bw,
    const float* __restrict__ Wout, const float* __restrict__ bout,
    float* __restrict__ memA, float* __restrict__ memB,
    float* __restrict__ w_r, float* __restrict__ w_w, float* __restrict__ r,
    float* __restrict__ h, float* __restrict__ Pp, float* __restrict__ Xc,
    float* __restrict__ eaG, float* __restrict__ out, unsigned* __restrict__ bar,
    int CH, int split)
{
    __shared__ SMem sm;
    int bid = blockIdx.x, tid = threadIdx.x;
    int tx = tid & 15, ty = tid >> 4;
    unsigned* cnt = bar;
    unsigned* gen = bar + 1;

    for (int t = 0; t < T_; t++) {
        float* mold = split ? ((t & 1) ? memB : memA) : memA;   // s_t
        float* mnew = split ? ((t & 1) ? memA : memB) : memA;   // s_{t+1} target

        // ---- phase 0 (every CH steps): Xc chunk = x[:, t..t+CH) @ Wc_x ----
        if ((t & (CH - 1)) == 0) {
            int ntile = CH * 16;
            for (int tile = bid; tile < ntile; tile += NBLK) {
                int row0 = (tile >> 4) * 128;
                int col0 = (tile & 15) * 128;
                float acc[8][8];
#pragma unroll
                for (int i = 0; i < 8; i++)
#pragma unroll
                    for (int j = 0; j < 8; j++) acc[i][j] = 0.f;
                for (int k0 = 0; k0 < IN_; k0 += 16) {
#pragma unroll
                    for (int l = 0; l < 8; l++) {
                        int e = tid + l * 256;
                        int rr = e >> 4, kk = e & 15;
                        int rg = row0 + rr;
                        int tl = rg >> 7, bb = rg & 127;
                        sm.p2.As[kk][rr] = x[((size_t)bb * T_ + t + tl) * IN_ + k0 + kk];
                    }
#pragma unroll
                    for (int l = 0; l < 8; l++) {
                        int e = tid + l * 256;
                        int kk = e >> 7, cc = e & 127;
                        sm.p2.Bs[kk][cc] = Wc[(size_t)(M_ + k0 + kk) * C_ + col0 + cc];
                    }
                    __syncthreads();
#pragma unroll
                    for (int kk = 0; kk < 16; kk++) {
                        float4 alo = *(const float4*)&sm.p2.As[kk][ty * 4];
                        float4 ahi = *(const float4*)&sm.p2.As[kk][64 + ty * 4];
                        float4 blo = *(const float4*)&sm.p2.Bs[kk][tx * 4];
                        float4 bhi = *(const float4*)&sm.p2.Bs[kk][64 + tx * 4];
                        float av[8] = {alo.x, alo.y, alo.z, alo.w, ahi.x, ahi.y, ahi.z, ahi.w};
                        float bv[8] = {blo.x, blo.y, blo.z, blo.w, bhi.x, bhi.y, bhi.z, bhi.w};
#pragma unroll
                        for (int i = 0; i < 8; i++)
#pragma unroll
                            for (int j = 0; j < 8; j++) acc[i][j] += av[i] * bv[j];
                    }
                    __syncthreads();
                }
#pragma unroll
                for (int i = 0; i < 8; i++) {
                    int gr = row0 + ((i < 4) ? (ty * 4 + i) : (64 + ty * 4 + i - 4));
                    float* dst = Xc + (size_t)gr * C_ + col0;
                    *(float4*)&dst[tx * 4]      = make_float4(acc[i][0], acc[i][1], acc[i][2], acc[i][3]);
                    *(float4*)&dst[64 + tx * 4] = make_float4(acc[i][4], acc[i][5], acc[i][6], acc[i][7]);
                }
            }
            grid_barrier(cnt, gen);
        }

        // ---- phase 1: h = tanh(r @ Wc_r + Xc_t + bc), one 32x32 tile per block ----
        {
            const float* XcT = Xc + (size_t)(t & (CH - 1)) * B_ * C_;
            int col0 = (bid & 63) * 32;
            int row0 = (bid >> 6) * 32;
            float acc00 = 0.f, acc01 = 0.f, acc10 = 0.f, acc11 = 0.f;
            for (int k0 = 0; k0 < M_; k0 += 16) {
#pragma unroll
                for (int l = 0; l < 2; l++) {
                    int e = tid + l * 256;
                    sm.p1.As[e & 15][e >> 4] = r[(size_t)(row0 + (e >> 4)) * M_ + k0 + (e & 15)];
                    sm.p1.Bs[e >> 5][e & 31] = Wc[(size_t)(k0 + (e >> 5)) * C_ + col0 + (e & 31)];
                }
                __syncthreads();
#pragma unroll
                for (int kk = 0; kk < 16; kk++) {
                    float2 a2 = *(const float2*)&sm.p1.As[kk][ty * 2];
                    float2 b2 = *(const float2*)&sm.p1.Bs[kk][tx * 2];
                    acc00 += a2.x * b2.x; acc01 += a2.x * b2.y;
                    acc10 += a2.y * b2.x; acc11 += a2.y * b2.y;
                }
                __syncthreads();
            }
            {
                int gr = row0 + ty * 2, gc = col0 + tx * 2;
                float2 xc2 = *(const float2*)&XcT[(size_t)gr * C_ + gc];
                float2 bc2 = *(const float2*)&bc[gc];
                float2 o; o.x = tanhf(acc00 + xc2.x + bc2.x); o.y = tanhf(acc01 + xc2.y + bc2.y);
                *(float2*)&h[(size_t)gr * C_ + gc] = o;
                gr++;
                xc2 = *(const float2*)&XcT[(size_t)gr * C_ + gc];
                o.x = tanhf(acc10 + xc2.x + bc2.x); o.y = tanhf(acc11 + xc2.y + bc2.y);
                *(float2*)&h[(size_t)gr * C_ + gc] = o;
            }
        }
        grid_barrier(cnt, gen);

        // ---- phase 2: P-GEMM (blocks 0..143) ----
        if (bid < P2BLK) {
            int col0 = (bid % 9) * 128;
            int z = bid / 9;
            float acc[8][8];
#pragma unroll
            for (int i = 0; i < 8; i++)
#pragma unroll
                for (int j = 0; j < 8; j++) acc[i][j] = 0.f;
            int kbase = z * (C_ / ZP);
            for (int k0 = kbase; k0 < kbase + C_ / ZP; k0 += 16) {
#pragma unroll
                for (int l = 0; l < 8; l++) {
                    int e = tid + l * 256;
                    int rr = e >> 4, kk = e & 15;
                    sm.p2.As[kk][rr] = h[(size_t)rr * C_ + k0 + kk];
                }
#pragma unroll
                for (int l = 0; l < 8; l++) {
                    int e = tid + l * 256;
                    int kk = e >> 7, cc = e & 127;
                    int gc = col0 + cc, gk = k0 + kk;
                    float v = 0.f;
                    if (gc < PR)            v = Wr[(size_t)gk * PR + gc];
                    else if (gc < PR + PWW) v = Ww[(size_t)gk * PWW + (gc - PR)];
                    else if (gc < PTOT)     v = Wout[(size_t)gk * OUT_ + (gc - PR - PWW)];
                    sm.p2.Bs[kk][cc] = v;
                }
                __syncthreads();
#pragma unroll
                for (int kk = 0; kk < 16; kk++) {
                    float4 alo = *(const float4*)&sm.p2.As[kk][ty * 4];
                    float4 ahi = *(const float4*)&sm.p2.As[kk][64 + ty * 4];
                    float4 blo = *(const float4*)&sm.p2.Bs[kk][tx * 4];
                    float4 bhi = *(const float4*)&sm.p2.Bs[kk][64 + tx * 4];
                    float av[8] = {alo.x, alo.y, alo.z, alo.w, ahi.x, ahi.y, ahi.z, ahi.w};
                    float bv[8] = {blo.x, blo.y, blo.z, blo.w, bhi.x, bhi.y, bhi.z, bhi.w};
#pragma unroll
                    for (int i = 0; i < 8; i++)
#pragma unroll
                        for (int j = 0; j < 8; j++) acc[i][j] += av[i] * bv[j];
                }
                __syncthreads();
            }
            float* Pdst = Pp + (size_t)z * B_ * COLP;
#pragma unroll
            for (int i = 0; i < 8; i++) {
                int gr = (i < 4) ? (ty * 4 + i) : (64 + ty * 4 + i - 4);
                float* dst = Pdst + (size_t)gr * COLP + col0;
                *(float4*)&dst[tx * 4]      = make_float4(acc[i][0], acc[i][1], acc[i][2], acc[i][3]);
                *(float4*)&dst[64 + tx * 4] = make_float4(acc[i][4], acc[i][5], acc[i][6], acc[i][7]);
            }
        }
        grid_barrier(cnt, gen);

        // ---- phase 3a: addressing ----
        if (split) {
            int b = bid & 127;
            const float* Pb = Pp + (size_t)b * COLP;
            if (bid < 128) {
                // read head: w_r, r_new (from s_t), out
                for (int c = tid; c < PR; c += 256) {
                    float v = br[c];
#pragma unroll
                    for (int z = 0; z < ZP; z++) v += Pb[(size_t)z * B_ * COLP + c];
                    sm.p3.p[c] = v;
                }
                __syncthreads();
                compute_w(sm.p3, mold, w_r, b);
                {
                    int m = tid & (M_ - 1), half = tid >> 7;
                    const float* mb = mold + (size_t)b * N_ * M_;
                    float acc = 0.f;
                    int n0 = half * 128;
#pragma unroll 4
                    for (int n = n0; n < n0 + 128; n++) acc += sm.p3.wsh[n] * mb[(size_t)n * M_ + m];
                    sm.p3.p[tid] = acc;
                    __syncthreads();
                    if (tid < M_) r[(size_t)b * M_ + tid] = sm.p3.p[tid] + sm.p3.p[tid + 128];
                }
                for (int j = tid; j < OUT_; j += 256) {
                    float v = bout[j];
#pragma unroll
                    for (int z = 0; z < ZP; z++) v += Pb[(size_t)z * B_ * COLP + PR + PWW + j];
                    out[((size_t)b * T_ + t) * OUT_ + j] = v;
                }
            } else {
                // write head: compute w_w, e, a; publish to global for phase 3b
                for (int c = tid; c < PWW; c += 256) {
                    float v = bw[c];
#pragma unroll
                    for (int z = 0; z < ZP; z++) v += Pb[(size_t)z * B_ * COLP + PR + c];
                    sm.p3.p[c] = v;
                }
                __syncthreads();
                compute_w(sm.p3, mold, w_w, b);
                if (tid < M_) {
                    eaG[(b << 8) | tid]        = sigmoidf(sm.p3.p[PR + tid]);
                    eaG[(b << 8) | (M_ + tid)] = tanhf(sm.p3.p[PR + M_ + tid]);
                }
            }
            grid_barrier(cnt, gen);

            // ---- phase 3b: mem update s_{t+1} = U_t(s_t), all 256 blocks ----
            {
                const float4* ms4 = (const float4*)mold;
                float4* md4 = (float4*)mnew;
                const size_t total = (size_t)B_ * N_ * M_ / 4;   // 2^20
                size_t i = (size_t)bid * 256 + tid;
                const size_t stride = (size_t)NBLK * 256;
                for (; i < total; i += stride) {
                    int b2 = (int)(i >> 13);          // 8192 float4 per batch
                    int rem = (int)(i & 8191);
                    int n = rem >> 5;
                    int mq = (rem & 31) << 2;
                    float wv = w_w[(b2 << 8) | n];
                    float4 v = ms4[i];
                    float4 e4 = *(const float4*)&eaG[(b2 << 8) | mq];
                    float4 a4 = *(const float4*)&eaG[(b2 << 8) | (M_ + mq)];
                    v.x = v.x * (1.f - wv * e4.x) + wv * a4.x;
                    v.y = v.y * (1.f - wv * e4.y) + wv * a4.y;
                    v.z = v.z * (1.f - wv * e4.z) + wv * a4.z;
                    v.w = v.w * (1.f - wv * e4.w) + wv * a4.w;
                    md4[i] = v;
                }
            }
        } else if (bid < 128) {
            // sequential fallback: read head then write head in-place (round-1 validated)
            int b = bid;
            const float* Pb = Pp + (size_t)b * COLP;
            for (int c = tid; c < PR; c += 256) {
                float v = br[c];
#pragma unroll
                for (int z = 0; z < ZP; z++) v += Pb[(size_t)z * B_ * COLP + c];
                sm.p3.p[c] = v;
            }
            __syncthreads();
            compute_w(sm.p3, memA, w_r, b);
            {
                int m = tid & (M_ - 1), half = tid >> 7;
                const float* mb = memA + (size_t)b * N_ * M_;
                float acc = 0.f;
                int n0 = half * 128;
#pragma unroll 4
                for (int n = n0; n < n0 + 128; n++) acc += sm.p3.wsh[n] * mb[(size_t)n * M_ + m];
                sm.p3.p[tid] = acc;
                __syncthreads();
                if (tid < M_) r[(size_t)b * M_ + tid] = sm.p3.p[tid] + sm.p3.p[tid + 128];
            }
            for (int j = tid; j < OUT_; j += 256) {
                float v = bout[j];
#pragma unroll
                for (int z = 0; z < ZP; z++) v += Pb[(size_t)z * B_ * COLP + PR + PWW + j];
                out[((size_t)b * T_ + t) * OUT_ + j] = v;
            }
            __syncthreads();
            for (int c = tid; c < PWW; c += 256) {
                float v = bw[c];
#pragma unroll
                for (int z = 0; z < ZP; z++) v += Pb[(size_t)z * B_ * COLP + PR + c];
                sm.p3.p[c] = v;
            }
            __syncthreads();
            compute_w(sm.p3, memA, w_w, b);
            float ev = 0.f, av = 0.f;
            if (tid < M_) { ev = sigmoidf(sm.p3.p[PR + tid]); av = tanhf(sm.p3.p[PR + M_ + tid]); }
            __syncthreads();
            if (tid < M_) { sm.p3.p[tid] = ev; sm.p3.p[M_ + tid] = av; }
            __syncthreads();
            float4* mb4 = (float4*)(memA + (size_t)b * N_ * M_);
            for (int idx = tid; idx < N_ * M_ / 4; idx += 256) {
                int n = idx >> 5;
                int mq = (idx & 31) << 2;
                float wv = sm.p3.wsh[n];
                float4 v = mb4[idx];
                float4 e4 = *(const float4*)&sm.p3.p[mq];
                float4 a4 = *(const float4*)&sm.p3.p[M_ + mq];
                v.x = v.x * (1.f - wv * e4.x) + wv * a4.x;
                v.y = v.y * (1.f - wv * e4.y) + wv * a4.y;
                v.z = v.z * (1.f - wv * e4.z) + wv * a4.z;
                v.w = v.w * (1.f - wv * e4.w) + wv * a4.w;
                mb4[idx] = v;
            }
        }
        grid_barrier(cnt, gen);
    }
}

// ---------------- launch ----------------
static const float* by_size(void* const* d_in, const int* in_sizes, int n_in,
                            long long want, int fallback)
{
    for (int i = 0; i < n_in; i++)
        if ((long long)in_sizes[i] == want) return (const float*)d_in[i];
    return (const float*)d_in[fallback];
}

extern "C" void kernel_launch(void* const* d_in, const int* in_sizes, int n_in,
                              void* d_out, int out_size, void* d_ws, size_t ws_size,
                              hipStream_t stream)
{
    const float* x         = by_size(d_in, in_sizes, n_in, (long long)B_ * T_ * IN_, 0);
    const float* Wc        = by_size(d_in, in_sizes, n_in, (long long)(M_ + IN_) * C_, 1);
    const float* bc        = by_size(d_in, in_sizes, n_in, C_, 2);
    const float* Wout      = by_size(d_in, in_sizes, n_in, (long long)C_ * OUT_, 3);
    const float* bout      = by_size(d_in, in_sizes, n_in, OUT_, 4);
    const float* Wr        = by_size(d_in, in_sizes, n_in, (long long)C_ * PR, 5);
    const float* br        = by_size(d_in, in_sizes, n_in, PR, 6);
    const float* Ww        = by_size(d_in, in_sizes, n_in, (long long)C_ * PWW, 7);
    const float* bw        = by_size(d_in, in_sizes, n_in, PWW, 8);
    const float* mem_init  = by_size(d_in, in_sizes, n_in, N_ * M_, 9);
    const float* read_init = by_size(d_in, in_sizes, n_in, M_, 10);
    float* out = (float*)d_out;

    auto pad = [](size_t s) { return (s + 255) & ~(size_t)255; };
    const size_t SZ_MEM = (size_t)B_ * N_ * M_ * sizeof(float);
    const size_t SZ_R   = (size_t)B_ * M_ * sizeof(float);
    const size_t SZ_W   = (size_t)B_ * N_ * sizeof(float);
    const size_t SZ_H   = (size_t)B_ * C_ * sizeof(float);
    const size_t SZ_PP  = (size_t)ZP * B_ * COLP * sizeof(float);
    const size_t SZ_EA  = (size_t)B_ * 2 * M_ * sizeof(float);
    const size_t SZ_BAR = 256;
    const size_t SZ_XC1 = (size_t)B_ * C_ * sizeof(float);   // one timestep of Xc

    size_t fixedsz = pad(SZ_MEM) + pad(SZ_R) + 2 * pad(SZ_W) + pad(SZ_H)
                   + pad(SZ_PP) + pad(SZ_EA) + pad(SZ_BAR);
    int split = (fixedsz + pad(SZ_MEM) + pad(SZ_XC1) <= ws_size) ? 1 : 0;
    size_t used = fixedsz + (split ? pad(SZ_MEM) : 0);
    size_t rem = (ws_size > used) ? (ws_size - used) : 0;
    int CH = 1;
    while (CH < T_ && pad((size_t)(CH * 2) * SZ_XC1) <= rem) CH <<= 1;

    char* p = (char*)d_ws;
    auto alloc = [&](size_t bytes) -> void* {
        void* q = (void*)p;
        p += pad(bytes);
        return q;
    };
    float*    memA = (float*)alloc(SZ_MEM);
    float*    r    = (float*)alloc(SZ_R);
    float*    w_r  = (float*)alloc(SZ_W);
    float*    w_w  = (float*)alloc(SZ_W);
    float*    h    = (float*)alloc(SZ_H);
    float*    Pp   = (float*)alloc(SZ_PP);
    float*    eaG  = (float*)alloc(SZ_EA);
    unsigned* bar  = (unsigned*)alloc(SZ_BAR);
    float*    memB = split ? (float*)alloc(SZ_MEM) : memA;
    float*    Xc   = (float*)alloc((size_t)CH * SZ_XC1);

    init_state<<<1024, 256, 0, stream>>>(memA, w_r, w_w, r, bar, mem_init, read_init);

    ntm_persistent<<<NBLK, 256, 0, stream>>>(
        x, Wc, bc, Wr, br, Ww, bw, Wout, bout,
        memA, memB, w_r, w_w, r, h, Pp, Xc, eaG, out, bar, CH, split);
}

// Round 4
// 50417.294 us; speedup vs baseline: 2.2389x; 2.2389x over previous
//
#include <hip/hip_runtime.h>
#include <math.h>

#define B_   128
#define T_   256
#define IN_  512
#define C_   2048
#define N_   256
#define M_   128
#define OUT_ 512
#define PR   134          // M_+6
#define PWW  390          // 3M+6
#define PTOT 1036         // PR + PWW + OUT_
#define COLP 1152         // padded P columns (9 tiles of 128)
#define ZP   16           // split-K partials for GEMM2
#define NBLK 256
#define P2BLK 144         // blocks running the P-GEMM in phase 2
#define EPSF 1e-8f

__device__ __forceinline__ float softplusf(float x) { return (x > 20.f) ? x : log1pf(expf(x)); }
__device__ __forceinline__ float sigmoidf(float x) { return 1.f / (1.f + expf(-x)); }

// ---------------- grid-wide barrier: monotonic counter, minimal cache ops ----------------
// ONE release fence (L2 wb) + ONE acquire fence (L2 inv) per block per barrier.
// Poll is RELAXED (plain coherent load, NO buffer_inv per iteration — round-3's bug).
__device__ __forceinline__ void grid_barrier(unsigned* cnt, unsigned target)
{
    __syncthreads();
    if (threadIdx.x == 0) {
        __builtin_amdgcn_fence(__ATOMIC_RELEASE, "agent");   // wb dirty L2 once
        __hip_atomic_fetch_add(cnt, 1u, __ATOMIC_RELAXED, __HIP_MEMORY_SCOPE_AGENT);
        while (__hip_atomic_load(cnt, __ATOMIC_RELAXED, __HIP_MEMORY_SCOPE_AGENT) < target)
            __builtin_amdgcn_s_sleep(4);
        __builtin_amdgcn_fence(__ATOMIC_ACQUIRE, "agent");   // inv L1/L2 once
    }
    __syncthreads();
}

// ---------------- init: state + barrier word ----------------
__global__ __launch_bounds__(256) void init_state(
    float* __restrict__ mem, float* __restrict__ w_r, float* __restrict__ w_w,
    float* __restrict__ r, unsigned* __restrict__ bar,
    const float* __restrict__ mem_init, const float* __restrict__ read_init)
{
    int i0 = blockIdx.x * blockDim.x + threadIdx.x;
    int stride = gridDim.x * blockDim.x;
    for (int i = i0; i < B_ * N_ * M_; i += stride)
        mem[i] = mem_init[i & (N_ * M_ - 1)];
    for (int i = i0; i < B_ * N_; i += stride) { w_r[i] = 1.f / N_; w_w[i] = 1.f / N_; }
    for (int i = i0; i < B_ * M_; i += stride) r[i] = read_init[i & (M_ - 1)];
    if (i0 < 2) bar[i0] = 0u;
}

// ---------------- shared-memory union across phases ----------------
struct SM3 { float p[400]; float wsh[N_]; float red[8]; };
union SMem {
    struct { float As[16][36];  float Bs[16][36];  } p1;   // h-GEMM
    struct { float As[16][132]; float Bs[16][132]; } p2;   // P-GEMM / Xc-GEMM
    SM3 p3;                                                // addressing
};

__device__ __forceinline__ float redSum(SM3& s, float v, int slot) {
#pragma unroll
    for (int off = 32; off; off >>= 1) v += __shfl_xor(v, off, 64);
    if ((threadIdx.x & 63) == 0) s.red[slot * 4 + (threadIdx.x >> 6)] = v;
    __syncthreads();
    return (s.red[slot * 4] + s.red[slot * 4 + 1]) + (s.red[slot * 4 + 2] + s.red[slot * 4 + 3]);
}
__device__ __forceinline__ float redMax(SM3& s, float v, int slot) {
#pragma unroll
    for (int off = 32; off; off >>= 1) v = fmaxf(v, __shfl_xor(v, off, 64));
    if ((threadIdx.x & 63) == 0) s.red[slot * 4 + (threadIdx.x >> 6)] = v;
    __syncthreads();
    return fmaxf(fmaxf(s.red[slot * 4], s.red[slot * 4 + 1]),
                 fmaxf(s.red[slot * 4 + 2], s.red[slot * 4 + 3]));
}

// addressing math over s.p[0..134); leaves final w in s.wsh and wglob
__device__ __forceinline__ void compute_w(
    SM3& s, const float* __restrict__ mem, float* __restrict__ wglob, int b)
{
    int tid = threadIdx.x;
    float kv = (tid < M_) ? s.p[tid] : 0.f;
    float knorm = sqrtf(redSum(s, kv * kv, 0));
    float beta = softplusf(s.p[M_]);
    float g    = sigmoidf(s.p[M_ + 1]);
    float a0 = s.p[M_ + 2], a1 = s.p[M_ + 3], a2 = s.p[M_ + 4];
    float mx3 = fmaxf(a0, fmaxf(a1, a2));
    float e0 = expf(a0 - mx3), e1 = expf(a1 - mx3), e2 = expf(a2 - mx3);
    float inv3 = 1.f / (e0 + e1 + e2);
    float s0 = e0 * inv3, s1 = e1 * inv3, s2 = e2 * inv3;
    float gamma = 1.f + softplusf(s.p[M_ + 5]);

    const float* mrow = mem + ((size_t)b * N_ + tid) * M_;
    float dot = 0.f, nrm = 0.f;
#pragma unroll 8
    for (int m = 0; m < M_; m += 4) {
        float4 v = *(const float4*)&mrow[m];
        float4 kk = *(const float4*)&s.p[m];
        dot += v.x * kk.x + v.y * kk.y + v.z * kk.z + v.w * kk.w;
        nrm += v.x * v.x + v.y * v.y + v.z * v.z + v.w * v.w;
    }
    float sim = dot / (knorm * sqrtf(nrm) + EPSF);
    float zz = beta * sim;
    float mx = redMax(s, zz, 1);
    float ez = expf(zz - mx);
    float wc = ez / redSum(s, ez, 0);
    float wgv = g * wc + (1.f - g) * wglob[(size_t)b * N_ + tid];
    s.wsh[tid] = wgv;
    __syncthreads();
    float wt = s0 * s.wsh[(tid + 1) & (N_ - 1)]
             + s1 * wgv
             + s2 * s.wsh[(tid + N_ - 1) & (N_ - 1)];
    float wp = powf(wt + EPSF, gamma);
    float wfin = wp / redSum(s, wp, 1);   // internal barrier covers wsh reads above
    wglob[(size_t)b * N_ + tid] = wfin;
    s.wsh[tid] = wfin;
    __syncthreads();
}

// ---------------- persistent kernel (regular launch): whole T loop ----------------
__global__ __launch_bounds__(256, 1) void ntm_persistent(
    const float* __restrict__ x,  const float* __restrict__ Wc,  const float* __restrict__ bc,
    const float* __restrict__ Wr, const float* __restrict__ br,
    const float* __restrict__ Ww, const float* __restrict__ bw,
    const float* __restrict__ Wout, const float* __restrict__ bout,
    float* __restrict__ memA, float* __restrict__ memB,
    float* __restrict__ w_r, float* __restrict__ w_w, float* __restrict__ r,
    float* __restrict__ h, float* __restrict__ Pp, float* __restrict__ Xc,
    float* __restrict__ eaG, float* __restrict__ out, unsigned* __restrict__ bar,
    int CH, int split)
{
    __shared__ SMem sm;
    int bid = blockIdx.x, tid = threadIdx.x;
    int tx = tid & 15, ty = tid >> 4;
    unsigned ep = 0;   // barrier epoch (call sites are grid-uniform)

    for (int t = 0; t < T_; t++) {
        float* mold = split ? ((t & 1) ? memB : memA) : memA;   // s_t
        float* mnew = split ? ((t & 1) ? memA : memB) : memA;   // s_{t+1} target

        // ---- phase 0 (every CH steps): Xc chunk = x[:, t..t+CH) @ Wc_x ----
        if ((t & (CH - 1)) == 0) {
            int ntile = CH * 16;
            for (int tile = bid; tile < ntile; tile += NBLK) {
                int row0 = (tile >> 4) * 128;
                int col0 = (tile & 15) * 128;
                float acc[8][8];
#pragma unroll
                for (int i = 0; i < 8; i++)
#pragma unroll
                    for (int j = 0; j < 8; j++) acc[i][j] = 0.f;
                for (int k0 = 0; k0 < IN_; k0 += 16) {
#pragma unroll
                    for (int l = 0; l < 8; l++) {
                        int e = tid + l * 256;
                        int rr = e >> 4, kk = e & 15;
                        int rg = row0 + rr;
                        int tl = rg >> 7, bb = rg & 127;
                        sm.p2.As[kk][rr] = x[((size_t)bb * T_ + t + tl) * IN_ + k0 + kk];
                    }
#pragma unroll
                    for (int l = 0; l < 8; l++) {
                        int e = tid + l * 256;
                        int kk = e >> 7, cc = e & 127;
                        sm.p2.Bs[kk][cc] = Wc[(size_t)(M_ + k0 + kk) * C_ + col0 + cc];
                    }
                    __syncthreads();
#pragma unroll
                    for (int kk = 0; kk < 16; kk++) {
                        float4 alo = *(const float4*)&sm.p2.As[kk][ty * 4];
                        float4 ahi = *(const float4*)&sm.p2.As[kk][64 + ty * 4];
                        float4 blo = *(const float4*)&sm.p2.Bs[kk][tx * 4];
                        float4 bhi = *(const float4*)&sm.p2.Bs[kk][64 + tx * 4];
                        float av[8] = {alo.x, alo.y, alo.z, alo.w, ahi.x, ahi.y, ahi.z, ahi.w};
                        float bv[8] = {blo.x, blo.y, blo.z, blo.w, bhi.x, bhi.y, bhi.z, bhi.w};
#pragma unroll
                        for (int i = 0; i < 8; i++)
#pragma unroll
                            for (int j = 0; j < 8; j++) acc[i][j] += av[i] * bv[j];
                    }
                    __syncthreads();
                }
#pragma unroll
                for (int i = 0; i < 8; i++) {
                    int gr = row0 + ((i < 4) ? (ty * 4 + i) : (64 + ty * 4 + i - 4));
                    float* dst = Xc + (size_t)gr * C_ + col0;
                    *(float4*)&dst[tx * 4]      = make_float4(acc[i][0], acc[i][1], acc[i][2], acc[i][3]);
                    *(float4*)&dst[64 + tx * 4] = make_float4(acc[i][4], acc[i][5], acc[i][6], acc[i][7]);
                }
            }
            ep += NBLK; grid_barrier(bar, ep);
        }

        // ---- phase 1: h = tanh(r @ Wc_r + Xc_t + bc), one 32x32 tile per block ----
        {
            const float* XcT = Xc + (size_t)(t & (CH - 1)) * B_ * C_;
            int col0 = (bid & 63) * 32;
            int row0 = (bid >> 6) * 32;
            float acc00 = 0.f, acc01 = 0.f, acc10 = 0.f, acc11 = 0.f;
            for (int k0 = 0; k0 < M_; k0 += 16) {
#pragma unroll
                for (int l = 0; l < 2; l++) {
                    int e = tid + l * 256;
                    sm.p1.As[e & 15][e >> 4] = r[(size_t)(row0 + (e >> 4)) * M_ + k0 + (e & 15)];
                    sm.p1.Bs[e >> 5][e & 31] = Wc[(size_t)(k0 + (e >> 5)) * C_ + col0 + (e & 31)];
                }
                __syncthreads();
#pragma unroll
                for (int kk = 0; kk < 16; kk++) {
                    float2 a2 = *(const float2*)&sm.p1.As[kk][ty * 2];
                    float2 b2 = *(const float2*)&sm.p1.Bs[kk][tx * 2];
                    acc00 += a2.x * b2.x; acc01 += a2.x * b2.y;
                    acc10 += a2.y * b2.x; acc11 += a2.y * b2.y;
                }
                __syncthreads();
            }
            {
                int gr = row0 + ty * 2, gc = col0 + tx * 2;
                float2 xc2 = *(const float2*)&XcT[(size_t)gr * C_ + gc];
                float2 bc2 = *(const float2*)&bc[gc];
                float2 o; o.x = tanhf(acc00 + xc2.x + bc2.x); o.y = tanhf(acc01 + xc2.y + bc2.y);
                *(float2*)&h[(size_t)gr * C_ + gc] = o;
                gr++;
                xc2 = *(const float2*)&XcT[(size_t)gr * C_ + gc];
                o.x = tanhf(acc10 + xc2.x + bc2.x); o.y = tanhf(acc11 + xc2.y + bc2.y);
                *(float2*)&h[(size_t)gr * C_ + gc] = o;
            }
        }
        ep += NBLK; grid_barrier(bar, ep);

        // ---- phase 2: P-GEMM (blocks 0..143) ----
        if (bid < P2BLK) {
            int col0 = (bid % 9) * 128;
            int z = bid / 9;
            float acc[8][8];
#pragma unroll
            for (int i = 0; i < 8; i++)
#pragma unroll
                for (int j = 0; j < 8; j++) acc[i][j] = 0.f;
            int kbase = z * (C_ / ZP);
            for (int k0 = kbase; k0 < kbase + C_ / ZP; k0 += 16) {
#pragma unroll
                for (int l = 0; l < 8; l++) {
                    int e = tid + l * 256;
                    int rr = e >> 4, kk = e & 15;
                    sm.p2.As[kk][rr] = h[(size_t)rr * C_ + k0 + kk];
                }
#pragma unroll
                for (int l = 0; l < 8; l++) {
                    int e = tid + l * 256;
                    int kk = e >> 7, cc = e & 127;
                    int gc = col0 + cc, gk = k0 + kk;
                    float v = 0.f;
                    if (gc < PR)            v = Wr[(size_t)gk * PR + gc];
                    else if (gc < PR + PWW) v = Ww[(size_t)gk * PWW + (gc - PR)];
                    else if (gc < PTOT)     v = Wout[(size_t)gk * OUT_ + (gc - PR - PWW)];
                    sm.p2.Bs[kk][cc] = v;
                }
                __syncthreads();
#pragma unroll
                for (int kk = 0; kk < 16; kk++) {
                    float4 alo = *(const float4*)&sm.p2.As[kk][ty * 4];
                    float4 ahi = *(const float4*)&sm.p2.As[kk][64 + ty * 4];
                    float4 blo = *(const float4*)&sm.p2.Bs[kk][tx * 4];
                    float4 bhi = *(const float4*)&sm.p2.Bs[kk][64 + tx * 4];
                    float av[8] = {alo.x, alo.y, alo.z, alo.w, ahi.x, ahi.y, ahi.z, ahi.w};
                    float bv[8] = {blo.x, blo.y, blo.z, blo.w, bhi.x, bhi.y, bhi.z, bhi.w};
#pragma unroll
                    for (int i = 0; i < 8; i++)
#pragma unroll
                        for (int j = 0; j < 8; j++) acc[i][j] += av[i] * bv[j];
                }
                __syncthreads();
            }
            float* Pdst = Pp + (size_t)z * B_ * COLP;
#pragma unroll
            for (int i = 0; i < 8; i++) {
                int gr = (i < 4) ? (ty * 4 + i) : (64 + ty * 4 + i - 4);
                float* dst = Pdst + (size_t)gr * COLP + col0;
                *(float4*)&dst[tx * 4]      = make_float4(acc[i][0], acc[i][1], acc[i][2], acc[i][3]);
                *(float4*)&dst[64 + tx * 4] = make_float4(acc[i][4], acc[i][5], acc[i][6], acc[i][7]);
            }
        }
        ep += NBLK; grid_barrier(bar, ep);

        // ---- phase 3a: addressing ----
        if (split) {
            int b = bid & 127;
            const float* Pb = Pp + (size_t)b * COLP;
            if (bid < 128) {
                // read head: w_r, r_new (from s_t), out
                for (int c = tid; c < PR; c += 256) {
                    float v = br[c];
#pragma unroll
                    for (int z = 0; z < ZP; z++) v += Pb[(size_t)z * B_ * COLP + c];
                    sm.p3.p[c] = v;
                }
                __syncthreads();
                compute_w(sm.p3, mold, w_r, b);
                {
                    int m = tid & (M_ - 1), half = tid >> 7;
                    const float* mb = mold + (size_t)b * N_ * M_;
                    float acc = 0.f;
                    int n0 = half * 128;
#pragma unroll 4
                    for (int n = n0; n < n0 + 128; n++) acc += sm.p3.wsh[n] * mb[(size_t)n * M_ + m];
                    sm.p3.p[tid] = acc;
                    __syncthreads();
                    if (tid < M_) r[(size_t)b * M_ + tid] = sm.p3.p[tid] + sm.p3.p[tid + 128];
                }
                for (int j = tid; j < OUT_; j += 256) {
                    float v = bout[j];
#pragma unroll
                    for (int z = 0; z < ZP; z++) v += Pb[(size_t)z * B_ * COLP + PR + PWW + j];
                    out[((size_t)b * T_ + t) * OUT_ + j] = v;
                }
            } else {
                // write head: compute w_w, e, a; publish to global for phase 3b
                for (int c = tid; c < PWW; c += 256) {
                    float v = bw[c];
#pragma unroll
                    for (int z = 0; z < ZP; z++) v += Pb[(size_t)z * B_ * COLP + PR + c];
                    sm.p3.p[c] = v;
                }
                __syncthreads();
                compute_w(sm.p3, mold, w_w, b);
                if (tid < M_) {
                    eaG[(b << 8) | tid]        = sigmoidf(sm.p3.p[PR + tid]);
                    eaG[(b << 8) | (M_ + tid)] = tanhf(sm.p3.p[PR + M_ + tid]);
                }
            }

            // ---- phase 3b: mem update s_{t+1} = U_t(s_t) — skipped for the
            // final step (its result is never read; out/r/w already stored) ----
            if (t < T_ - 1) {
                ep += NBLK; grid_barrier(bar, ep);
                const float4* ms4 = (const float4*)mold;
                float4* md4 = (float4*)mnew;
                const size_t total = (size_t)B_ * N_ * M_ / 4;   // 2^20
                size_t i = (size_t)bid * 256 + tid;
                const size_t stride = (size_t)NBLK * 256;
                for (; i < total; i += stride) {
                    int b2 = (int)(i >> 13);          // 8192 float4 per batch
                    int rem = (int)(i & 8191);
                    int n = rem >> 5;
                    int mq = (rem & 31) << 2;
                    float wv = w_w[(b2 << 8) | n];
                    float4 v = ms4[i];
                    float4 e4 = *(const float4*)&eaG[(b2 << 8) | mq];
                    float4 a4 = *(const float4*)&eaG[(b2 << 8) | (M_ + mq)];
                    v.x = v.x * (1.f - wv * e4.x) + wv * a4.x;
                    v.y = v.y * (1.f - wv * e4.y) + wv * a4.y;
                    v.z = v.z * (1.f - wv * e4.z) + wv * a4.z;
                    v.w = v.w * (1.f - wv * e4.w) + wv * a4.w;
                    md4[i] = v;
                }
                ep += NBLK; grid_barrier(bar, ep);
            }
        } else {
            if (bid < 128) {
                // sequential fallback: read head then write head in-place (round-1 validated)
                int b = bid;
                const float* Pb = Pp + (size_t)b * COLP;
                for (int c = tid; c < PR; c += 256) {
                    float v = br[c];
#pragma unroll
                    for (int z = 0; z < ZP; z++) v += Pb[(size_t)z * B_ * COLP + c];
                    sm.p3.p[c] = v;
                }
                __syncthreads();
                compute_w(sm.p3, memA, w_r, b);
                {
                    int m = tid & (M_ - 1), half = tid >> 7;
                    const float* mb = memA + (size_t)b * N_ * M_;
                    float acc = 0.f;
                    int n0 = half * 128;
#pragma unroll 4
                    for (int n = n0; n < n0 + 128; n++) acc += sm.p3.wsh[n] * mb[(size_t)n * M_ + m];
                    sm.p3.p[tid] = acc;
                    __syncthreads();
                    if (tid < M_) r[(size_t)b * M_ + tid] = sm.p3.p[tid] + sm.p3.p[tid + 128];
                }
                for (int j = tid; j < OUT_; j += 256) {
                    float v = bout[j];
#pragma unroll
                    for (int z = 0; z < ZP; z++) v += Pb[(size_t)z * B_ * COLP + PR + PWW + j];
                    out[((size_t)b * T_ + t) * OUT_ + j] = v;
                }
                __syncthreads();
                for (int c = tid; c < PWW; c += 256) {
                    float v = bw[c];
#pragma unroll
                    for (int z = 0; z < ZP; z++) v += Pb[(size_t)z * B_ * COLP + PR + c];
                    sm.p3.p[c] = v;
                }
                __syncthreads();
                compute_w(sm.p3, memA, w_w, b);
                float ev = 0.f, av = 0.f;
                if (tid < M_) { ev = sigmoidf(sm.p3.p[PR + tid]); av = tanhf(sm.p3.p[PR + M_ + tid]); }
                __syncthreads();
                if (tid < M_) { sm.p3.p[tid] = ev; sm.p3.p[M_ + tid] = av; }
                __syncthreads();
                float4* mb4 = (float4*)(memA + (size_t)b * N_ * M_);
                for (int idx = tid; idx < N_ * M_ / 4; idx += 256) {
                    int n = idx >> 5;
                    int mq = (idx & 31) << 2;
                    float wv = sm.p3.wsh[n];
                    float4 v = mb4[idx];
                    float4 e4 = *(const float4*)&sm.p3.p[mq];
                    float4 a4 = *(const float4*)&sm.p3.p[M_ + mq];
                    v.x = v.x * (1.f - wv * e4.x) + wv * a4.x;
                    v.y = v.y * (1.f - wv * e4.y) + wv * a4.y;
                    v.z = v.z * (1.f - wv * e4.z) + wv * a4.z;
                    v.w = v.w * (1.f - wv * e4.w) + wv * a4.w;
                    mb4[idx] = v;
                }
            }
        }
        ep += NBLK; grid_barrier(bar, ep);
    }
}

// ---------------- launch ----------------
static const float* by_size(void* const* d_in, const int* in_sizes, int n_in,
                            long long want, int fallback)
{
    for (int i = 0; i < n_in; i++)
        if ((long long)in_sizes[i] == want) return (const float*)d_in[i];
    return (const float*)d_in[fallback];
}

extern "C" void kernel_launch(void* const* d_in, const int* in_sizes, int n_in,
                              void* d_out, int out_size, void* d_ws, size_t ws_size,
                              hipStream_t stream)
{
    const float* x         = by_size(d_in, in_sizes, n_in, (long long)B_ * T_ * IN_, 0);
    const float* Wc        = by_size(d_in, in_sizes, n_in, (long long)(M_ + IN_) * C_, 1);
    const float* bc        = by_size(d_in, in_sizes, n_in, C_, 2);
    const float* Wout      = by_size(d_in, in_sizes, n_in, (long long)C_ * OUT_, 3);
    const float* bout      = by_size(d_in, in_sizes, n_in, OUT_, 4);
    const float* Wr        = by_size(d_in, in_sizes, n_in, (long long)C_ * PR, 5);
    const float* br        = by_size(d_in, in_sizes, n_in, PR, 6);
    const float* Ww        = by_size(d_in, in_sizes, n_in, (long long)C_ * PWW, 7);
    const float* bw        = by_size(d_in, in_sizes, n_in, PWW, 8);
    const float* mem_init  = by_size(d_in, in_sizes, n_in, N_ * M_, 9);
    const float* read_init = by_size(d_in, in_sizes, n_in, M_, 10);
    float* out = (float*)d_out;

    auto pad = [](size_t s) { return (s + 255) & ~(size_t)255; };
    const size_t SZ_MEM = (size_t)B_ * N_ * M_ * sizeof(float);
    const size_t SZ_R   = (size_t)B_ * M_ * sizeof(float);
    const size_t SZ_W   = (size_t)B_ * N_ * sizeof(float);
    const size_t SZ_H   = (size_t)B_ * C_ * sizeof(float);
    const size_t SZ_PP  = (size_t)ZP * B_ * COLP * sizeof(float);
    const size_t SZ_EA  = (size_t)B_ * 2 * M_ * sizeof(float);
    const size_t SZ_BAR = 256;
    const size_t SZ_XC1 = (size_t)B_ * C_ * sizeof(float);   // one timestep of Xc

    size_t fixedsz = pad(SZ_MEM) + pad(SZ_R) + 2 * pad(SZ_W) + pad(SZ_H)
                   + pad(SZ_PP) + pad(SZ_EA) + pad(SZ_BAR);
    int split = (fixedsz + pad(SZ_MEM) + pad(SZ_XC1) <= ws_size) ? 1 : 0;
    size_t used = fixedsz + (split ? pad(SZ_MEM) : 0);
    size_t rem = (ws_size > used) ? (ws_size - used) : 0;
    int CH = 1;
    while (CH < T_ && pad((size_t)(CH * 2) * SZ_XC1) <= rem) CH <<= 1;

    char* p = (char*)d_ws;
    auto alloc = [&](size_t bytes) -> void* {
        void* q = (void*)p;
        p += pad(bytes);
        return q;
    };
    float*    memA = (float*)alloc(SZ_MEM);
    float*    r    = (float*)alloc(SZ_R);
    float*    w_r  = (float*)alloc(SZ_W);
    float*    w_w  = (float*)alloc(SZ_W);
    float*    h    = (float*)alloc(SZ_H);
    float*    Pp   = (float*)alloc(SZ_PP);
    float*    eaG  = (float*)alloc(SZ_EA);
    unsigned* bar  = (unsigned*)alloc(SZ_BAR);
    float*    memB = split ? (float*)alloc(SZ_MEM) : memA;
    float*    Xc   = (float*)alloc((size_t)CH * SZ_XC1);

    init_state<<<1024, 256, 0, stream>>>(memA, w_r, w_w, r, bar, mem_init, read_init);

    ntm_persistent<<<NBLK, 256, 0, stream>>>(
        x, Wc, bc, Wr, br, Ww, bw, Wout, bout,
        memA, memB, w_r, w_w, r, h, Pp, Xc, eaG, out, bar, CH, split);
}

// Round 7
// 21032.401 us; speedup vs baseline: 5.3670x; 2.3971x over previous
//
#include <hip/hip_runtime.h>
#include <math.h>

#define B_   128
#define T_   256
#define IN_  512
#define C_   2048
#define N_   256
#define M_   128
#define OUT_ 512
#define PR   134          // M_+6
#define PWW  390          // 3M+6
#define PTOT 1036         // PR + PWW + OUT_
#define COLP 1152         // padded P columns (9 tiles of 128)
#define ZP   16           // split-K partials for GEMM2
#define UBLK 1024         // update-streaming blocks in gemm_h_upd
#define EPSF 1e-8f

__device__ __forceinline__ float softplusf(float x) { return (x > 20.f) ? x : log1pf(expf(x)); }
__device__ __forceinline__ float sigmoidf(float x) { return 1.f / (1.f + expf(-x)); }

// ---------------- init ----------------
__global__ __launch_bounds__(256) void init_state(
    float* __restrict__ mem, float* __restrict__ w_r, float* __restrict__ w_w,
    float* __restrict__ r,
    const float* __restrict__ mem_init, const float* __restrict__ read_init)
{
    int i0 = blockIdx.x * blockDim.x + threadIdx.x;
    int stride = gridDim.x * blockDim.x;
    for (int i = i0; i < B_ * N_ * M_; i += stride)
        mem[i] = mem_init[i & (N_ * M_ - 1)];
    for (int i = i0; i < B_ * N_; i += stride) { w_r[i] = 1.f / N_; w_w[i] = 1.f / N_; }
    for (int i = i0; i < B_ * M_; i += stride) r[i] = read_init[i & (M_ - 1)];
}

// ---------------- chunk precompute: Xc = x[:, t0..t0+CH) @ Wc_x (validated r1) ----------------
// grid (16, CH); tile 128x128, 8x8/thread, K=512
__global__ __launch_bounds__(256) void gemm_xc(
    const float* __restrict__ x, const float* __restrict__ Wc,
    float* __restrict__ Xc, int t0)
{
    __shared__ __align__(16) float As[16][132];
    __shared__ __align__(16) float Bs[16][132];
    int col0 = blockIdx.x * 128;
    int row0 = blockIdx.y * 128;
    int tid = threadIdx.x, tx = tid & 15, ty = tid >> 4;
    float acc[8][8];
#pragma unroll
    for (int i = 0; i < 8; i++)
#pragma unroll
        for (int j = 0; j < 8; j++) acc[i][j] = 0.f;

    for (int k0 = 0; k0 < IN_; k0 += 16) {
#pragma unroll
        for (int l = 0; l < 8; l++) {
            int e = tid + l * 256;
            int rr = e >> 4, kk = e & 15;
            int rg = row0 + rr;
            int tl = rg >> 7, bb = rg & 127;
            As[kk][rr] = x[((size_t)bb * T_ + t0 + tl) * IN_ + k0 + kk];
        }
#pragma unroll
        for (int l = 0; l < 8; l++) {
            int e = tid + l * 256;
            int kk = e >> 7, cc = e & 127;
            Bs[kk][cc] = Wc[(size_t)(M_ + k0 + kk) * C_ + col0 + cc];
        }
        __syncthreads();
#pragma unroll
        for (int kk = 0; kk < 16; kk++) {
            float4 alo = *(const float4*)&As[kk][ty * 4];
            float4 ahi = *(const float4*)&As[kk][64 + ty * 4];
            float4 blo = *(const float4*)&Bs[kk][tx * 4];
            float4 bhi = *(const float4*)&Bs[kk][64 + tx * 4];
            float av[8] = {alo.x, alo.y, alo.z, alo.w, ahi.x, ahi.y, ahi.z, ahi.w};
            float bv[8] = {blo.x, blo.y, blo.z, blo.w, bhi.x, bhi.y, bhi.z, bhi.w};
#pragma unroll
            for (int i = 0; i < 8; i++)
#pragma unroll
                for (int j = 0; j < 8; j++) acc[i][j] += av[i] * bv[j];
        }
        __syncthreads();
    }
#pragma unroll
    for (int i = 0; i < 8; i++) {
        int gr = row0 + ((i < 4) ? (ty * 4 + i) : (64 + ty * 4 + i - 4));
        float* dst = Xc + (size_t)gr * C_ + col0;
        *(float4*)&dst[tx * 4]      = make_float4(acc[i][0], acc[i][1], acc[i][2], acc[i][3]);
        *(float4*)&dst[64 + tx * 4] = make_float4(acc[i][4], acc[i][5], acc[i][6], acc[i][7]);
    }
}

// ---------------- fused: h-GEMM (blocks 0..255) + deferred mem-update(t-1) (256..1279) ----
// h = tanh(r @ Wc_r + Xc_t + bc)  [validated r1 gemm_h, grid (64,4) flattened]
// update: mem = mem*(1 - w_w*e) + w_w*a  in place  [validated r4 phase-3b math]
__global__ __launch_bounds__(256) void gemm_h_upd(
    const float* __restrict__ r, const float* __restrict__ Wc,
    const float* __restrict__ XcT, const float* __restrict__ bc,
    float* __restrict__ h,
    float* __restrict__ mem, const float* __restrict__ w_w,
    const float* __restrict__ eaG, int do_upd)
{
    __shared__ __align__(16) float As[16][36];
    __shared__ __align__(16) float Bs[16][36];
    int bid = blockIdx.x, tid = threadIdx.x;
    if (bid < 256) {
        int col0 = (bid & 63) * 32;
        int row0 = (bid >> 6) * 32;
        int tx = tid & 15, ty = tid >> 4;
        float acc00 = 0.f, acc01 = 0.f, acc10 = 0.f, acc11 = 0.f;
        for (int k0 = 0; k0 < M_; k0 += 16) {
#pragma unroll
            for (int l = 0; l < 2; l++) {
                int e = tid + l * 256;
                As[e & 15][e >> 4] = r[(size_t)(row0 + (e >> 4)) * M_ + k0 + (e & 15)];
                Bs[e >> 5][e & 31] = Wc[(size_t)(k0 + (e >> 5)) * C_ + col0 + (e & 31)];
            }
            __syncthreads();
#pragma unroll
            for (int kk = 0; kk < 16; kk++) {
                float2 a2 = *(const float2*)&As[kk][ty * 2];
                float2 b2 = *(const float2*)&Bs[kk][tx * 2];
                acc00 += a2.x * b2.x; acc01 += a2.x * b2.y;
                acc10 += a2.y * b2.x; acc11 += a2.y * b2.y;
            }
            __syncthreads();
        }
        {
            int gr = row0 + ty * 2, gc = col0 + tx * 2;
            float2 xc2 = *(const float2*)&XcT[(size_t)gr * C_ + gc];
            float2 bc2 = *(const float2*)&bc[gc];
            float2 o;
            o.x = tanhf(acc00 + xc2.x + bc2.x); o.y = tanhf(acc01 + xc2.y + bc2.y);
            *(float2*)&h[(size_t)gr * C_ + gc] = o;
            gr++;
            xc2 = *(const float2*)&XcT[(size_t)gr * C_ + gc];
            o.x = tanhf(acc10 + xc2.x + bc2.x); o.y = tanhf(acc11 + xc2.y + bc2.y);
            *(float2*)&h[(size_t)gr * C_ + gc] = o;
        }
    } else if (do_upd) {
        const size_t total = (size_t)B_ * N_ * M_ / 4;   // 2^20 float4
        float4* m4 = (float4*)mem;
        size_t i = (size_t)(bid - 256) * 256 + tid;
        const size_t stride = (size_t)UBLK * 256;
        for (; i < total; i += stride) {
            int b2 = (int)(i >> 13);          // 8192 float4 per batch
            int rem = (int)(i & 8191);
            int n = rem >> 5;
            int mq = (rem & 31) << 2;
            float wv = w_w[(b2 << 8) | n];
            float4 v = m4[i];
            float4 e4 = *(const float4*)&eaG[(b2 << 8) | mq];
            float4 a4 = *(const float4*)&eaG[(b2 << 8) | (M_ + mq)];
            v.x = v.x * (1.f - wv * e4.x) + wv * a4.x;
            v.y = v.y * (1.f - wv * e4.y) + wv * a4.y;
            v.z = v.z * (1.f - wv * e4.z) + wv * a4.z;
            v.w = v.w * (1.f - wv * e4.w) + wv * a4.w;
            m4[i] = v;
        }
    }
}

// ---------------- Ppart[z] = h @ [Wr|Ww|Wout] (validated r1), grid (9,1,16) ----------------
__global__ __launch_bounds__(256) void gemm_p(
    const float* __restrict__ h,
    const float* __restrict__ Wr, const float* __restrict__ Ww, const float* __restrict__ Wout,
    float* __restrict__ Ppart)
{
    __shared__ __align__(16) float As[16][132];
    __shared__ __align__(16) float Bs[16][132];
    int col0 = blockIdx.x * 128;
    int z = blockIdx.z;
    int tid = threadIdx.x, tx = tid & 15, ty = tid >> 4;
    float acc[8][8];
#pragma unroll
    for (int i = 0; i < 8; i++)
#pragma unroll
        for (int j = 0; j < 8; j++) acc[i][j] = 0.f;

    int kbase = z * (C_ / ZP);
    for (int k0 = kbase; k0 < kbase + C_ / ZP; k0 += 16) {
#pragma unroll
        for (int l = 0; l < 8; l++) {
            int e = tid + l * 256;
            int rr = e >> 4, kk = e & 15;
            As[kk][rr] = h[(size_t)rr * C_ + k0 + kk];
        }
#pragma unroll
        for (int l = 0; l < 8; l++) {
            int e = tid + l * 256;
            int kk = e >> 7, cc = e & 127;
            int gc = col0 + cc, gk = k0 + kk;
            float v = 0.f;
            if (gc < PR)            v = Wr[(size_t)gk * PR + gc];
            else if (gc < PR + PWW) v = Ww[(size_t)gk * PWW + (gc - PR)];
            else if (gc < PTOT)     v = Wout[(size_t)gk * OUT_ + (gc - PR - PWW)];
            Bs[kk][cc] = v;
        }
        __syncthreads();
#pragma unroll
        for (int kk = 0; kk < 16; kk++) {
            float4 alo = *(const float4*)&As[kk][ty * 4];
            float4 ahi = *(const float4*)&As[kk][64 + ty * 4];
            float4 blo = *(const float4*)&Bs[kk][tx * 4];
            float4 bhi = *(const float4*)&Bs[kk][64 + tx * 4];
            float av[8] = {alo.x, alo.y, alo.z, alo.w, ahi.x, ahi.y, ahi.z, ahi.w};
            float bv[8] = {blo.x, blo.y, blo.z, blo.w, bhi.x, bhi.y, bhi.z, bhi.w};
#pragma unroll
            for (int i = 0; i < 8; i++)
#pragma unroll
                for (int j = 0; j < 8; j++) acc[i][j] += av[i] * bv[j];
        }
        __syncthreads();
    }
    float* Pdst = Ppart + (size_t)z * B_ * COLP;
#pragma unroll
    for (int i = 0; i < 8; i++) {
        int gr = (i < 4) ? (ty * 4 + i) : (64 + ty * 4 + i - 4);
        float* dst = Pdst + (size_t)gr * COLP + col0;
        *(float4*)&dst[tx * 4]      = make_float4(acc[i][0], acc[i][1], acc[i][2], acc[i][3]);
        *(float4*)&dst[64 + tx * 4] = make_float4(acc[i][4], acc[i][5], acc[i][6], acc[i][7]);
    }
}

// ---------------- addressing heads (validated r4 phase-3a), grid (128,2) ----------------
struct SM3 { float p[400]; float wsh[N_]; float red[8]; };

__device__ __forceinline__ float redSum(SM3& s, float v, int slot) {
#pragma unroll
    for (int off = 32; off; off >>= 1) v += __shfl_xor(v, off, 64);
    if ((threadIdx.x & 63) == 0) s.red[slot * 4 + (threadIdx.x >> 6)] = v;
    __syncthreads();
    return (s.red[slot * 4] + s.red[slot * 4 + 1]) + (s.red[slot * 4 + 2] + s.red[slot * 4 + 3]);
}
__device__ __forceinline__ float redMax(SM3& s, float v, int slot) {
#pragma unroll
    for (int off = 32; off; off >>= 1) v = fmaxf(v, __shfl_xor(v, off, 64));
    if ((threadIdx.x & 63) == 0) s.red[slot * 4 + (threadIdx.x >> 6)] = v;
    __syncthreads();
    return fmaxf(fmaxf(s.red[slot * 4], s.red[slot * 4 + 1]),
                 fmaxf(s.red[slot * 4 + 2], s.red[slot * 4 + 3]));
}

__device__ __forceinline__ void compute_w(
    SM3& s, const float* __restrict__ mem, float* __restrict__ wglob, int b)
{
    int tid = threadIdx.x;
    float kv = (tid < M_) ? s.p[tid] : 0.f;
    float knorm = sqrtf(redSum(s, kv * kv, 0));
    float beta = softplusf(s.p[M_]);
    float g    = sigmoidf(s.p[M_ + 1]);
    float a0 = s.p[M_ + 2], a1 = s.p[M_ + 3], a2 = s.p[M_ + 4];
    float mx3 = fmaxf(a0, fmaxf(a1, a2));
    float e0 = expf(a0 - mx3), e1 = expf(a1 - mx3), e2 = expf(a2 - mx3);
    float inv3 = 1.f / (e0 + e1 + e2);
    float s0 = e0 * inv3, s1 = e1 * inv3, s2 = e2 * inv3;
    float gamma = 1.f + softplusf(s.p[M_ + 5]);

    const float* mrow = mem + ((size_t)b * N_ + tid) * M_;
    float dot = 0.f, nrm = 0.f;
#pragma unroll 8
    for (int m = 0; m < M_; m += 4) {
        float4 v = *(const float4*)&mrow[m];
        float4 kk = *(const float4*)&s.p[m];
        dot += v.x * kk.x + v.y * kk.y + v.z * kk.z + v.w * kk.w;
        nrm += v.x * v.x + v.y * v.y + v.z * v.z + v.w * v.w;
    }
    float sim = dot / (knorm * sqrtf(nrm) + EPSF);
    float zz = beta * sim;
    float mx = redMax(s, zz, 1);
    float ez = expf(zz - mx);
    float wc = ez / redSum(s, ez, 0);
    float wgv = g * wc + (1.f - g) * wglob[(size_t)b * N_ + tid];
    s.wsh[tid] = wgv;
    __syncthreads();
    float wt = s0 * s.wsh[(tid + 1) & (N_ - 1)]
             + s1 * wgv
             + s2 * s.wsh[(tid + N_ - 1) & (N_ - 1)];
    float wp = powf(wt + EPSF, gamma);
    float wfin = wp / redSum(s, wp, 1);   // internal barrier covers wsh reads above
    wglob[(size_t)b * N_ + tid] = wfin;
    s.wsh[tid] = wfin;
    __syncthreads();
}

__global__ __launch_bounds__(256) void addr_heads(
    const float* __restrict__ Ppart,
    const float* __restrict__ br, const float* __restrict__ bw, const float* __restrict__ bout,
    const float* __restrict__ mem,
    float* __restrict__ w_r, float* __restrict__ w_w,
    float* __restrict__ r_out, float* __restrict__ eaG,
    float* __restrict__ out, int t)
{
    __shared__ SM3 sm;
    int b = blockIdx.x, tid = threadIdx.x;
    const float* Pb = Ppart + (size_t)b * COLP;

    if (blockIdx.y == 0) {
        // read head: w_r, r_new (from current mem), out
        for (int c = tid; c < PR; c += 256) {
            float v = br[c];
#pragma unroll
            for (int z = 0; z < ZP; z++) v += Pb[(size_t)z * B_ * COLP + c];
            sm.p[c] = v;
        }
        __syncthreads();
        compute_w(sm, mem, w_r, b);
        {
            int m = tid & (M_ - 1), half = tid >> 7;
            const float* mb = mem + (size_t)b * N_ * M_;
            float acc = 0.f;
            int n0 = half * 128;
#pragma unroll 4
            for (int n = n0; n < n0 + 128; n++) acc += sm.wsh[n] * mb[(size_t)n * M_ + m];
            sm.p[tid] = acc;   // compute_w's trailing barrier passed all p-reads
            __syncthreads();
            if (tid < M_) r_out[(size_t)b * M_ + tid] = sm.p[tid] + sm.p[tid + 128];
        }
        for (int j = tid; j < OUT_; j += 256) {
            float v = bout[j];
#pragma unroll
            for (int z = 0; z < ZP; z++) v += Pb[(size_t)z * B_ * COLP + PR + PWW + j];
            out[((size_t)b * T_ + t) * OUT_ + j] = v;
        }
    } else {
        // write head: w_w, e, a (update itself is deferred to next step's gemm_h_upd)
        for (int c = tid; c < PWW; c += 256) {
            float v = bw[c];
#pragma unroll
            for (int z = 0; z < ZP; z++) v += Pb[(size_t)z * B_ * COLP + PR + c];
            sm.p[c] = v;
        }
        __syncthreads();
        compute_w(sm, mem, w_w, b);
        if (tid < M_) {
            eaG[(b << 8) | tid]        = sigmoidf(sm.p[PR + tid]);
            eaG[(b << 8) | (M_ + tid)] = tanhf(sm.p[PR + M_ + tid]);
        }
    }
}

// ---------------- launch ----------------
static const float* by_size(void* const* d_in, const int* in_sizes, int n_in,
                            long long want, int fallback)
{
    for (int i = 0; i < n_in; i++)
        if ((long long)in_sizes[i] == want) return (const float*)d_in[i];
    return (const float*)d_in[fallback];
}

extern "C" void kernel_launch(void* const* d_in, const int* in_sizes, int n_in,
                              void* d_out, int out_size, void* d_ws, size_t ws_size,
                              hipStream_t stream)
{
    const float* x         = by_size(d_in, in_sizes, n_in, (long long)B_ * T_ * IN_, 0);
    const float* Wc        = by_size(d_in, in_sizes, n_in, (long long)(M_ + IN_) * C_, 1);
    const float* bc        = by_size(d_in, in_sizes, n_in, C_, 2);
    const float* Wout      = by_size(d_in, in_sizes, n_in, (long long)C_ * OUT_, 3);
    const float* bout      = by_size(d_in, in_sizes, n_in, OUT_, 4);
    const float* Wr        = by_size(d_in, in_sizes, n_in, (long long)C_ * PR, 5);
    const float* br        = by_size(d_in, in_sizes, n_in, PR, 6);
    const float* Ww        = by_size(d_in, in_sizes, n_in, (long long)C_ * PWW, 7);
    const float* bw        = by_size(d_in, in_sizes, n_in, PWW, 8);
    const float* mem_init  = by_size(d_in, in_sizes, n_in, N_ * M_, 9);
    const float* read_init = by_size(d_in, in_sizes, n_in, M_, 10);
    float* out = (float*)d_out;

    auto pad = [](size_t s) { return (s + 255) & ~(size_t)255; };
    const size_t SZ_MEM = (size_t)B_ * N_ * M_ * sizeof(float);
    const size_t SZ_R   = (size_t)B_ * M_ * sizeof(float);
    const size_t SZ_W   = (size_t)B_ * N_ * sizeof(float);
    const size_t SZ_H   = (size_t)B_ * C_ * sizeof(float);
    const size_t SZ_PP  = (size_t)ZP * B_ * COLP * sizeof(float);
    const size_t SZ_EA  = (size_t)B_ * 2 * M_ * sizeof(float);
    const size_t SZ_XC1 = (size_t)B_ * C_ * sizeof(float);   // one timestep of Xc

    size_t fixedsz = pad(SZ_MEM) + pad(SZ_R) + 2 * pad(SZ_W) + pad(SZ_H)
                   + pad(SZ_PP) + pad(SZ_EA);
    size_t rem = (ws_size > fixedsz) ? (ws_size - fixedsz) : 0;
    int CH = 1;
    while (CH < T_ && pad((size_t)(CH * 2) * SZ_XC1) <= rem) CH <<= 1;

    char* p = (char*)d_ws;
    auto alloc = [&](size_t bytes) -> void* {
        void* q = (void*)p;
        p += pad(bytes);
        return q;
    };
    float* mem  = (float*)alloc(SZ_MEM);
    float* r    = (float*)alloc(SZ_R);
    float* w_r  = (float*)alloc(SZ_W);
    float* w_w  = (float*)alloc(SZ_W);
    float* h    = (float*)alloc(SZ_H);
    float* Pp   = (float*)alloc(SZ_PP);
    float* eaG  = (float*)alloc(SZ_EA);
    float* Xc   = (float*)alloc((size_t)CH * SZ_XC1);

    init_state<<<1024, 256, 0, stream>>>(mem, w_r, w_w, r, mem_init, read_init);

    for (int t = 0; t < T_; t++) {
        if ((t & (CH - 1)) == 0)
            gemm_xc<<<dim3(16, CH), 256, 0, stream>>>(x, Wc, Xc, t);
        gemm_h_upd<<<256 + UBLK, 256, 0, stream>>>(
            r, Wc, Xc + (size_t)(t & (CH - 1)) * B_ * C_, bc, h,
            mem, w_w, eaG, t > 0 ? 1 : 0);
        gemm_p<<<dim3(9, 1, ZP), 256, 0, stream>>>(h, Wr, Ww, Wout, Pp);
        addr_heads<<<dim3(128, 2), 256, 0, stream>>>(
            Pp, br, bw, bout, mem, w_r, w_w, r, eaG, out, t);
    }
}